// Round 5
// baseline (592.510 us; speedup 1.0000x reference)
//
#include <hip/hip_runtime.h>
#include <stdint.h>

typedef __fp16 f16x2 __attribute__((ext_vector_type(2)));
typedef __fp16 f16x8 __attribute__((ext_vector_type(8)));
typedef float  f32x4 __attribute__((ext_vector_type(4)));

#define NN   8192
#define INC  256
#define OUTC 256
#define K2   2048                    // INC * RR
#define YTN  ((size_t)OUTC * NN)     // 2M elements

__device__ __forceinline__ f16x8 cvt_f32x8_to_f16x8(f32x4 u0, f32x4 u1) {
    f16x8 out;
    f16x2* p = (f16x2*)&out;
    p[0] = __builtin_amdgcn_cvt_pkrtz(u0[0], u0[1]);
    p[1] = __builtin_amdgcn_cvt_pkrtz(u0[2], u0[3]);
    p[2] = __builtin_amdgcn_cvt_pkrtz(u1[0], u1[1]);
    p[3] = __builtin_amdgcn_cvt_pkrtz(u1[2], u1[3]);
    return out;
}

// ---------------------------------------------------------------------------
// W2T16[o][k] = sum_b w_rel[r,b] * w_bases[b,i,o],  k = i*8+r, f16 output.
// ---------------------------------------------------------------------------
__global__ void build_w2t16(const float* __restrict__ wb, const float* __restrict__ wr,
                            __fp16* __restrict__ W2T16) {
    int o = blockIdx.x;      // 0..255
    int i = threadIdx.x;     // 0..255
    float s[8];
#pragma unroll
    for (int r = 0; r < 8; ++r) s[r] = 0.f;
#pragma unroll
    for (int b = 0; b < 4; ++b) {
        float w = wb[((size_t)((b << 8) + i)) * OUTC + o];
#pragma unroll
        for (int r = 0; r < 8; ++r) s[r] = fmaf(wr[r * 4 + b], w, s[r]);
    }
    f16x8 out;
    f16x2* p = (f16x2*)&out;
    p[0] = __builtin_amdgcn_cvt_pkrtz(s[0], s[1]);
    p[1] = __builtin_amdgcn_cvt_pkrtz(s[2], s[3]);
    p[2] = __builtin_amdgcn_cvt_pkrtz(s[4], s[5]);
    p[3] = __builtin_amdgcn_cvt_pkrtz(s[6], s[7]);
    *reinterpret_cast<f16x8*>(&W2T16[(size_t)o * K2 + i * 8]) = out;
}

// ---------------------------------------------------------------------------
// GEMM1 (streaming, no LDS, no barriers):
//   yT_p[z][o][m] = W2T16[o][:] . x[m][:]   (M=256 o, N=8192 m, K=2048)
//   A = W2T16 f16 [256][2048] : L2-resident slice (128KB per (x,z) tile)
//   B = x      f32 [8192][2048]: streamed, cvt to f16 in-register
// Tile 128x128x32, 4 waves (2x2), wave 64x64, acc[4][4].
// Fragment loads go straight global->VGPR; each load instr = 64 lanes x 16B
// = 16 rows x 64B contiguous = 16 full cache lines (100% line utilization).
// No __syncthreads anywhere -> waves free-run; launch_bounds(256,4) caps
// VGPR <=128 -> 4 blocks/CU = 16 waves/CU for TLP latency hiding.
// ---------------------------------------------------------------------------
__global__ __launch_bounds__(256, 4)
void gemm1_stream(const __fp16* __restrict__ W2, const float* __restrict__ X,
                  float* __restrict__ Cp, int kPerSplit) {
    const int bm = blockIdx.x * 128;   // o
    const int bn = blockIdx.y * 128;   // m
    const int k0 = blockIdx.z * kPerSplit;

    const int tid  = threadIdx.x;
    const int lane = tid & 63;
    const int wave = tid >> 6;
    const int wm   = (wave >> 1) * 64;
    const int wn   = (wave & 1) * 64;
    const int quad = lane >> 4;
    const int l16  = lane & 15;

    f32x4 acc[4][4];
#pragma unroll
    for (int ti = 0; ti < 4; ++ti)
#pragma unroll
        for (int tj = 0; tj < 4; ++tj)
            acc[ti][tj] = (f32x4){0.f, 0.f, 0.f, 0.f};

    // per-lane base pointers (k-advance only inside the loop)
    const __fp16* aptr[4];
    const float*  bptr[4];
#pragma unroll
    for (int j = 0; j < 4; ++j) {
        aptr[j] = W2 + (size_t)(bm + wm + j * 16 + l16) * K2 + k0 + quad * 8;
        bptr[j] = X  + (size_t)(bn + wn + j * 16 + l16) * K2 + k0 + quad * 8;
    }

    for (int kc = 0; kc < kPerSplit; kc += 32) {
        f16x8 af[4];
        f16x8 bf[4];
#pragma unroll
        for (int j = 0; j < 4; ++j)
            af[j] = *(const f16x8*)(aptr[j] + kc);
#pragma unroll
        for (int j = 0; j < 4; ++j) {
            f32x4 u0 = *(const f32x4*)(bptr[j] + kc);
            f32x4 u1 = *(const f32x4*)(bptr[j] + kc + 4);
            bf[j] = cvt_f32x8_to_f16x8(u0, u1);
        }
#pragma unroll
        for (int ti = 0; ti < 4; ++ti)
#pragma unroll
            for (int tj = 0; tj < 4; ++tj)
                acc[ti][tj] = __builtin_amdgcn_mfma_f32_16x16x32_f16(
                    af[ti], bf[tj], acc[ti][tj], 0, 0, 0);
    }

    float* Cz = Cp + (size_t)blockIdx.z * 256 * NN;
#pragma unroll
    for (int ti = 0; ti < 4; ++ti)
#pragma unroll
        for (int tj = 0; tj < 4; ++tj)
#pragma unroll
            for (int r = 0; r < 4; ++r) {
                int row = bm + wm + ti * 16 + quad * 4 + r;   // o
                int col = bn + wn + tj * 16 + l16;            // m
                Cz[(size_t)row * NN + col] = acc[ti][tj][r];
            }
}

// ---------------------------------------------------------------------------
// GEMM2 (streaming, no LDS, no barriers):
//   out_p[z][n][o] = a[n][:] . yT16[o][:]   (M=8192 n, N=256 o, K=8192)
//   A = a    f32 [8192][8192]: streamed once from HBM, cvt in-register
//   B = yT16 f16 [256][8192] : L2-resident z-slice (0.5MB), read as fragments
// Tile 64x256x32 (full N per block -> `a` fetched exactly once), 4 waves,
// wave 32x128, acc[2][8] (64 VGPR). 16 waves/CU, free-running.
// ---------------------------------------------------------------------------
__global__ __launch_bounds__(256, 4)
void gemm2_stream(const float* __restrict__ A, const __fp16* __restrict__ Y,
                  float* __restrict__ Cp, int kPerSplit) {
    const int bm = blockIdx.x * 64;    // n
    const int k0 = blockIdx.z * kPerSplit;

    const int tid  = threadIdx.x;
    const int lane = tid & 63;
    const int wave = tid >> 6;
    const int wm   = (wave >> 1) * 32;    // 0 / 32
    const int wn   = (wave & 1) * 128;    // 0 / 128
    const int quad = lane >> 4;
    const int l16  = lane & 15;

    f32x4 acc[2][8];
#pragma unroll
    for (int ti = 0; ti < 2; ++ti)
#pragma unroll
        for (int tj = 0; tj < 8; ++tj)
            acc[ti][tj] = (f32x4){0.f, 0.f, 0.f, 0.f};

    const float*  aptr[2];
    const __fp16* bptr[8];
#pragma unroll
    for (int j = 0; j < 2; ++j)
        aptr[j] = A + (size_t)(bm + wm + j * 16 + l16) * NN + k0 + quad * 8;
#pragma unroll
    for (int j = 0; j < 8; ++j)
        bptr[j] = Y + (size_t)(wn + j * 16 + l16) * NN + k0 + quad * 8;

    for (int kc = 0; kc < kPerSplit; kc += 32) {
        f16x8 af[2];
        f16x8 bf[8];
#pragma unroll
        for (int j = 0; j < 2; ++j) {
            f32x4 u0 = *(const f32x4*)(aptr[j] + kc);
            f32x4 u1 = *(const f32x4*)(aptr[j] + kc + 4);
            af[j] = cvt_f32x8_to_f16x8(u0, u1);
        }
#pragma unroll
        for (int j = 0; j < 8; ++j)
            bf[j] = *(const f16x8*)(bptr[j] + kc);
#pragma unroll
        for (int ti = 0; ti < 2; ++ti)
#pragma unroll
            for (int tj = 0; tj < 8; ++tj)
                acc[ti][tj] = __builtin_amdgcn_mfma_f32_16x16x32_f16(
                    af[ti], bf[tj], acc[ti][tj], 0, 0, 0);
    }

    float* Cz = Cp + (size_t)blockIdx.z * NN * 256;
#pragma unroll
    for (int ti = 0; ti < 2; ++ti)
#pragma unroll
        for (int tj = 0; tj < 8; ++tj)
#pragma unroll
            for (int r = 0; r < 4; ++r) {
                int row = bm + wm + ti * 16 + quad * 4 + r;   // n
                int col = wn + tj * 16 + l16;                 // o
                Cz[(size_t)row * 256 + col] = acc[ti][tj][r];
            }
}

// ---------------------------------------------------------------------------
// yT16[i] = (f16) sum_{z<4} yT_p[z][i]
// ---------------------------------------------------------------------------
__global__ void reduce_yT(const float* __restrict__ yTp, __fp16* __restrict__ yT16) {
    size_t base = ((size_t)blockIdx.x * 256 + threadIdx.x) * 8;
    f32x4 s0 = (f32x4){0.f, 0.f, 0.f, 0.f};
    f32x4 s1 = (f32x4){0.f, 0.f, 0.f, 0.f};
#pragma unroll
    for (int z = 0; z < 4; ++z) {
        const float* p = yTp + (size_t)z * YTN + base;
        s0 += *(const f32x4*)p;
        s1 += *(const f32x4*)(p + 4);
    }
    *reinterpret_cast<f16x8*>(&yT16[base]) = cvt_f32x8_to_f16x8(s0, s1);
}

// ---------------------------------------------------------------------------
// out[i] = sum_{z<8} out_p[z][i]
// ---------------------------------------------------------------------------
__global__ void reduce_out(const float* __restrict__ op, float* __restrict__ out) {
    size_t base = ((size_t)blockIdx.x * 256 + threadIdx.x) * 4;
    f32x4 s = (f32x4){0.f, 0.f, 0.f, 0.f};
#pragma unroll
    for (int z = 0; z < 8; ++z)
        s += *(const f32x4*)(op + (size_t)z * YTN + base);
    *reinterpret_cast<f32x4*>(&out[base]) = s;
}

// ---------------------------------------------------------------------------
extern "C" void kernel_launch(void* const* d_in, const int* in_sizes, int n_in,
                              void* d_out, int out_size, void* d_ws, size_t ws_size,
                              hipStream_t stream) {
    const float* a  = (const float*)d_in[0];   // [8192][8192]
    const float* x  = (const float*)d_in[1];   // [8192][2048] (k = i*8+r contiguous)
    const float* wb = (const float*)d_in[2];   // [4][256][256]
    const float* wr = (const float*)d_in[3];   // [8][4]
    float* out = (float*)d_out;                // [8192][256]

    // ws layout (101 MB total):
    //   [0,   32MB)  yT_p   : 4 x [256][8192] fp32 partials
    //   [32,  36MB)  yT16   : [256][8192] f16
    //   [36, 100MB)  out_p  : 8 x [8192][256] fp32 partials
    //   [100,101MB)  W2T16  : [256][2048] f16
    char* w = (char*)d_ws;
    float*  yT_p  = (float*)(w);
    __fp16* yT16  = (__fp16*)(w + ((size_t)32 << 20));
    float*  out_p = (float*)(w + ((size_t)36 << 20));
    __fp16* W2T16 = (__fp16*)(w + ((size_t)100 << 20));

    // 1) basis-combined weights, f16, [o][k]
    build_w2t16<<<dim3(256), dim3(256), 0, stream>>>(wb, wr, W2T16);

    // 2) yT_p[z][o][m] = W2T16[o][:] . x[m][:]   M=256,N=8192,K=2048, split 4
    gemm1_stream<<<dim3(2, 64, 4), dim3(256), 0, stream>>>(W2T16, x, yT_p, 512);

    // 3) yT16 = f16(sum_z yT_p)
    reduce_yT<<<dim3(1024), dim3(256), 0, stream>>>(yT_p, yT16);

    // 4) out_p[z][n][o] = a[n][:] . yT16[o][:]   M=8192,N=256(full),K=8192, split 8
    gemm2_stream<<<dim3(128, 1, 8), dim3(256), 0, stream>>>(a, yT16, out_p, 1024);

    // 5) out = sum_z out_p
    reduce_out<<<dim3(2048), dim3(256), 0, stream>>>(out_p, out);
}